// Round 5
// baseline (102.445 us; speedup 1.0000x reference)
//
#include <hip/hip_runtime.h>
#include <hip/hip_bf16.h>

typedef __bf16 bf16x8 __attribute__((ext_vector_type(8)));
typedef float f32x4 __attribute__((ext_vector_type(4)));

#define HDIM 4096
#define EDIM 64
#define KBLK 128      // 4096 / 32
#define NW 4          // waves per block = K-split factor
#define KBW (KBLK/NW) // 32 kb-steps per wave

// ---------------------------------------------------------------------------
// Kernel 1: coalesced repack of W into MFMA B-frag layout (UNnormalized bf16)
// + per-block per-column sum-of-squares partials (fp32).
// ---------------------------------------------------------------------------
__global__ __launch_bounds__(256) void pack_w_kernel(const float* __restrict__ W,
                                                     __bf16* __restrict__ Wp,
                                                     float* __restrict__ partial) {
  const int b = blockIdx.x;        // 64 blocks x 64 rows of W
  const int t = threadIdx.x;
  const int e = t & 63;
  const int nt = e >> 4, col = e & 15;
  __shared__ float red[256];
  float s = 0.f;
  const int base = b * 64 * 64;
#pragma unroll
  for (int i = 0; i < 16; ++i) {
    int flat = base + i * 256 + t;         // coalesced
    float v = W[flat];
    s = fmaf(v, v, s);
    int r = flat >> 6;                     // k index
    int kb = r >> 5, g = (r >> 3) & 3, j = r & 7;
    Wp[(size_t)((nt * KBLK + kb) * 64 + col + 16 * g) * 8 + j] = (__bf16)v;
  }
  red[t] = s;
  __syncthreads();
  if (t < 64)
    partial[b * 64 + t] = red[t] + red[t + 64] + red[t + 128] + red[t + 192];
}

// ---------------------------------------------------------------------------
// Kernel 2: fused norm_h @ (Wp * invw) + epilogue.
// Block = 4 waves, 16 rows, K-split x4. A path: FULL-LINE coalesced
// global->reg (lane c: row c>>3, quad c&7 -> 16 full 64B lines/instr),
// reg -> XOR-swizzled LDS (quad ^= row&7; conflict-free), LDS -> frag regs
// read one kb-step ahead. Static-index rings (depth 2), no barriers in loop;
// all waits are compiler-counted (VGPR vmcnt / in-order DS lgkmcnt).
// C/D layout (m89): lane l, reg r -> row (l>>4)*4+r, col l&15.
// ---------------------------------------------------------------------------
__global__ __launch_bounds__(256, 4) void gate_main_kernel(
    const float* __restrict__ H, const __bf16* __restrict__ Wp,
    const float* __restrict__ G, const float* __restrict__ partial,
    float* __restrict__ out, size_t third) {
  const int lane = threadIdx.x & 63;
  const int w = threadIdx.x >> 6;        // wave id = K-slice id
  const int m = lane & 15;
  const int g = lane >> 4;
  const int row0 = blockIdx.x * 16;

  __shared__ __align__(16) float lds_stage[NW][2][512];  // 16 KB (2 slots/wave)
  __shared__ float lds_acc[16][NW][64];                  // 16 KB
  __shared__ float lds_ssq[NW][16];
  __shared__ float lds_invw[64];

  const int kb0 = w * KBW;

  // --- staging geometry ---
  // global load: lane c -> row (c>>3), quad (c&7): full-line coalesced
  const float* srcA = H + (size_t)(row0 + (lane >> 3)) * HDIM + kb0 * 32 + (lane & 7) * 4;
  const float* srcB = srcA + (size_t)8 * HDIM;  // rows 8..15
  // LDS write: quad' = quad ^ (row&7)  (XOR swizzle, 16B granularity)
  const int wq = (lane & 7) ^ (lane >> 3);
  const int woffA = (lane >> 3) * 32 + wq * 4;
  const int woffB = woffA + 256;
  // LDS frag read: lane (m,g) reads quads 2g, 2g+1 of row m (swizzled)
  const int sw = (m & 7) << 2;
  const int roff0 = m * 32 + ((8 * g) ^ sw);
  const int roff1 = m * 32 + ((8 * g + 4) ^ sw);

  float* sbase = &lds_stage[w][0][0];
  const bf16x8* bbase = reinterpret_cast<const bf16x8*>(Wp) + lane;

  f32x4 acc[4] = {};
  float ssq0 = 0.f, ssq1 = 0.f;
  float4 ga[2][2];   // global-stage ring (literal indices only)
  float4 fr0[2], fr1[2];  // frag ring (literal indices only)

  // --- prologue: load data(0),data(1); commit+read data(0) ---
  ga[0][0] = *(const float4*)(srcA);
  ga[0][1] = *(const float4*)(srcB);
  ga[1][0] = *(const float4*)(srcA + 32);
  ga[1][1] = *(const float4*)(srcB + 32);
  {
    float* d0 = sbase;
    *(float4*)(d0 + woffA) = ga[0][0];
    *(float4*)(d0 + woffB) = ga[0][1];
    fr0[0] = *(const float4*)(d0 + roff0);
    fr1[0] = *(const float4*)(d0 + roff1);
  }

#define STEP(I, P, Q) {                                                        \
    float* dq = sbase + (Q) * 512;                                             \
    *(float4*)(dq + woffA) = ga[Q][0];   /* commit data(I+1) */                \
    *(float4*)(dq + woffB) = ga[Q][1];                                         \
    int jn = ((I) + 2 < KBW) ? (I) + 2 : KBW - 1;                              \
    ga[P][0] = *(const float4*)(srcA + (size_t)jn * 32);                       \
    ga[P][1] = *(const float4*)(srcB + (size_t)jn * 32);                       \
    fr0[Q] = *(const float4*)(dq + roff0);  /* read frag(I+1) ahead */         \
    fr1[Q] = *(const float4*)(dq + roff1);                                     \
    bf16x8 bfr[4];                                                             \
    _Pragma("unroll")                                                          \
    for (int nt = 0; nt < 4; ++nt)                                             \
      bfr[nt] = bbase[(size_t)(nt * KBLK + kb0 + (I)) * 64];                   \
    float4 x0 = fr0[P], x1 = fr1[P];        /* consume frag(I) */              \
    bf16x8 af;                                                                 \
    af[0] = (__bf16)x0.x; af[1] = (__bf16)x0.y;                                \
    af[2] = (__bf16)x0.z; af[3] = (__bf16)x0.w;                                \
    af[4] = (__bf16)x1.x; af[5] = (__bf16)x1.y;                                \
    af[6] = (__bf16)x1.z; af[7] = (__bf16)x1.w;                                \
    ssq0 = fmaf(x0.x, x0.x, ssq0); ssq1 = fmaf(x0.y, x0.y, ssq1);              \
    ssq0 = fmaf(x0.z, x0.z, ssq0); ssq1 = fmaf(x0.w, x0.w, ssq1);              \
    ssq0 = fmaf(x1.x, x1.x, ssq0); ssq1 = fmaf(x1.y, x1.y, ssq1);              \
    ssq0 = fmaf(x1.z, x1.z, ssq0); ssq1 = fmaf(x1.w, x1.w, ssq1);              \
    _Pragma("unroll")                                                          \
    for (int nt = 0; nt < 4; ++nt)                                             \
      acc[nt] = __builtin_amdgcn_mfma_f32_16x16x32_bf16(af, bfr[nt], acc[nt], 0, 0, 0); \
  }

  for (int t = 0; t < KBW / 2; ++t) {
    STEP(2 * t,     0, 1);
    STEP(2 * t + 1, 1, 0);
  }
#undef STEP

  // --- combine K-slices + epilogue ---
  float ssq = ssq0 + ssq1;
  ssq += __shfl_xor(ssq, 16, 64);
  ssq += __shfl_xor(ssq, 32, 64);

#pragma unroll
  for (int nt = 0; nt < 4; ++nt)
#pragma unroll
    for (int r = 0; r < 4; ++r) lds_acc[nt * 4 + r][w][lane] = acc[nt][r];
  if (g == 0) lds_ssq[w][m] = ssq;

  // W-column inv-norms (each wave covers its 16 columns)
  {
    float cs = 0.f;
    const float* pp = partial + (w * 16 + m);
#pragma unroll 8
    for (int i = 0; i < 64; ++i) cs += pp[i * 64];
    if (g == 0) lds_invw[w * 16 + m] = 1.0f / fmaxf(sqrtf(cs), 1e-12f);
  }
  __syncthreads();

  // Epilogue: lane = output column e; wave w stores rows {4w..4w+3} as
  // full 256-B contiguous stores per output tensor.
  {
    const float invw = lds_invw[lane];
    const float sg = 1.0f / (1.0f + __expf(-G[lane]));
#pragma unroll
    for (int rr = 0; rr < 4; ++rr) {
      const int R = w * 4 + rr;
      float st = 0.f, a = 0.f;
      const int fr = (lane >> 4) * 4 + (R & 3);
      const int i2 = ((R & 12) << 2) + (lane & 15);
#pragma unroll
      for (int ws = 0; ws < NW; ++ws) {
        st += lds_ssq[ws][R];
        a += lds_acc[fr][ws][i2];
      }
      float invh = 1.0f / fmaxf(sqrtf(st), 1e-12f);
      float raw = a * invh * invw;
      float sig = 1.0f / (1.0f + __expf(-raw));
      size_t idx = (size_t)(row0 + R) * EDIM + lane;
      out[idx] = raw;
      out[idx + third] = sig;
      out[idx + 2 * third] = fmaxf(sig - sg, 0.0f);
    }
  }
}

extern "C" void kernel_launch(void* const* d_in, const int* in_sizes, int n_in,
                              void* d_out, int out_size, void* d_ws, size_t ws_size,
                              hipStream_t stream) {
  const float* H = (const float*)d_in[0];   // [B*S, 4096]
  const float* W = (const float*)d_in[1];   // [4096, 64]
  const float* G = (const float*)d_in[2];   // [64]
  float* out = (float*)d_out;               // 3 x [B*S, 64] concatenated
  __bf16* Wp = (__bf16*)d_ws;               // 512 KB packed (unnormalized) W
  float* partial = (float*)((char*)d_ws + 512 * 1024);  // 64 blocks x 64 cols

  int rows = in_sizes[0] / HDIM;            // 16384
  size_t third = (size_t)out_size / 3;      // 1048576

  pack_w_kernel<<<64, 256, 0, stream>>>(W, Wp, partial);
  gate_main_kernel<<<rows / 16, 256, 0, stream>>>(H, Wp, G, partial, out, third);
}